// Round 1
// baseline (357.466 us; speedup 1.0000x reference)
//
#include <hip/hip_runtime.h>
#include <cstdint>
#include <cstddef>

typedef __attribute__((ext_vector_type(4))) float  f32x4;
typedef __attribute__((ext_vector_type(8))) short  s16x8;
typedef __attribute__((ext_vector_type(4))) short  s16x4;

#define EMB   1024
#define NHEAD 16
#define HD    64
#define NB    2
#define TT    2048
#define TQKV  3072   // packed Q|K|V column count

// ---------- helpers ----------
__device__ __forceinline__ short f2bf(float f) {
  union { float f; unsigned u; } x; x.f = f;
  unsigned r = x.u + 0x7FFFu + ((x.u >> 16) & 1u);
  return (short)(r >> 16);
}

__device__ __forceinline__ void gload_lds16(const short* g, short* l) {
  __builtin_amdgcn_global_load_lds(
      (const __attribute__((address_space(1))) void*)(g),
      (__attribute__((address_space(3))) void*)(l), 16, 0, 0);
}

// ---------- fp32 -> bf16 convert (vectorized) ----------
__global__ __launch_bounds__(256) void cvt4(const float* __restrict__ s,
                                            short* __restrict__ d, int n4) {
  int i = blockIdx.x * blockDim.x + threadIdx.x;
  if (i >= n4) return;
  f32x4 v = ((const f32x4*)s)[i];
  s16x4 o;
  o[0] = f2bf(v[0]); o[1] = f2bf(v[1]); o[2] = f2bf(v[2]); o[3] = f2bf(v[3]);
  ((s16x4*)d)[i] = o;
}

// ---------- GEMM  C[M,N] = A[M,K] @ B[N,K]^T  (bf16 in, f32 acc) ----------
// 128x128 tile, BK=32, 4 waves each 64x64 (4x4 frags of 16x16x32)
template <int OUT_BF16>
__global__ __launch_bounds__(256) void gemm_nt(const short* __restrict__ A,
                                               const short* __restrict__ B,
                                               void* __restrict__ C,
                                               int M, int N, int K) {
  __shared__ short lA[128 * 32];
  __shared__ short lB[128 * 32];
  const int tid  = threadIdx.x;
  const int lane = tid & 63;
  const int wid  = tid >> 6;
  const int bm = blockIdx.y, bn = blockIdx.x;
  const int wm = wid >> 1, wn = wid & 1;

  f32x4 acc[4][4];
#pragma unroll
  for (int i = 0; i < 4; ++i)
#pragma unroll
    for (int j = 0; j < 4; ++j) acc[i][j] = (f32x4){0.f, 0.f, 0.f, 0.f};

  const short* Ab = A + (size_t)bm * 128 * K;
  const short* Bb = B + (size_t)bn * 128 * K;
  const int srow = tid >> 2;        // 0..63
  const int scol = (tid & 3) * 8;   // 0,8,16,24

  for (int k0 = 0; k0 < K; k0 += 32) {
    __syncthreads();
    gload_lds16(Ab + (size_t)srow * K + k0 + scol,        lA + tid * 8);
    gload_lds16(Ab + (size_t)(srow + 64) * K + k0 + scol, lA + 2048 + tid * 8);
    gload_lds16(Bb + (size_t)srow * K + k0 + scol,        lB + tid * 8);
    gload_lds16(Bb + (size_t)(srow + 64) * K + k0 + scol, lB + 2048 + tid * 8);
    __syncthreads();

    s16x8 af[4], bf_[4];
#pragma unroll
    for (int i = 0; i < 4; ++i) {
      af[i]  = *(const s16x8*)(lA + (wm * 64 + i * 16 + (lane & 15)) * 32 + (lane >> 4) * 8);
      bf_[i] = *(const s16x8*)(lB + (wn * 64 + i * 16 + (lane & 15)) * 32 + (lane >> 4) * 8);
    }
#pragma unroll
    for (int i = 0; i < 4; ++i)
#pragma unroll
      for (int j = 0; j < 4; ++j)
        acc[i][j] = __builtin_amdgcn_mfma_f32_16x16x32_bf16(af[i], bf_[j], acc[i][j], 0, 0, 0);
  }

  const int row0 = bm * 128 + wm * 64;
  const int col0 = bn * 128 + wn * 64;
#pragma unroll
  for (int i = 0; i < 4; ++i)
#pragma unroll
    for (int j = 0; j < 4; ++j)
#pragma unroll
      for (int r = 0; r < 4; ++r) {
        int row = row0 + i * 16 + ((lane >> 4) << 2) + r;
        int col = col0 + j * 16 + (lane & 15);
        float v = acc[i][j][r];
        if (OUT_BF16) ((short*)C)[(size_t)row * N + col] = f2bf(v);
        else          ((float*)C)[(size_t)row * N + col] = v;
      }
}

// ---------- V transpose: Vt[bh][d][t] = QKV[b*T+t][2048 + h*64 + d] ----------
__global__ __launch_bounds__(256) void transpose_v(const short* __restrict__ qkv,
                                                   short* __restrict__ vt) {
  __shared__ short tile[64 * 72];
  const int tt = blockIdx.x, bh = blockIdx.y;
  const int b = bh >> 4, h = bh & 15;
  const int tid = threadIdx.x;

  const short* src = qkv + ((size_t)(b * TT + tt * 64)) * TQKV + 2048 + h * HD;
#pragma unroll
  for (int p = 0; p < 2; ++p) {
    int r = p * 32 + (tid >> 3);
    int c = (tid & 7) * 8;
    s16x8 v = *(const s16x8*)(src + (size_t)r * TQKV + c);
#pragma unroll
    for (int j = 0; j < 8; ++j) tile[r * 72 + c + j] = v[j];
  }
  __syncthreads();
  short* dst = vt + ((size_t)bh * HD) * TT + tt * 64;
#pragma unroll
  for (int p = 0; p < 2; ++p) {
    int d0 = p * 32 + (tid >> 3);
    int c  = (tid & 7) * 8;
    s16x8 o;
#pragma unroll
    for (int j = 0; j < 8; ++j) o[j] = tile[(c + j) * 72 + d0];
    *(s16x8*)(dst + (size_t)d0 * TT + c) = o;
  }
}

// ---------- attention pass 1: per-row online-softmax stats (m, l) ----------
__global__ __launch_bounds__(256) void attn_ml(const short* __restrict__ qkv,
                                               float* __restrict__ mbuf,
                                               float* __restrict__ lbuf) {
  __shared__ short lQ[64 * 64];
  __shared__ short lK[64 * 64];
  const int tid = threadIdx.x, lane = tid & 63, wid = tid >> 6;
  const int qt = blockIdx.x, bh = blockIdx.y;
  const int b = bh >> 4, h = bh & 15;

  const short* qsrc = qkv + ((size_t)(b * TT + qt * 64)) * TQKV + h * HD;
  gload_lds16(qsrc + (size_t)(tid >> 3) * TQKV + (tid & 7) * 8,        lQ + tid * 8);
  gload_lds16(qsrc + (size_t)((tid >> 3) + 32) * TQKV + (tid & 7) * 8, lQ + 2048 + tid * 8);
  __syncthreads();

  s16x8 aq[2];
  aq[0] = *(const s16x8*)(lQ + (wid * 16 + (lane & 15)) * 64 + (lane >> 4) * 8);
  aq[1] = *(const s16x8*)(lQ + (wid * 16 + (lane & 15)) * 64 + 32 + (lane >> 4) * 8);

  float m[4] = {-INFINITY, -INFINITY, -INFINITY, -INFINITY};
  float l[4] = {0.f, 0.f, 0.f, 0.f};
  const int qrow = qt * 64 + wid * 16 + ((lane >> 4) << 2);
  const short* ksrc0 = qkv + (size_t)(b * TT) * TQKV + EMB + h * HD;

  for (int kt = 0; kt <= qt; ++kt) {
    __syncthreads();
    const short* ks = ksrc0 + (size_t)(kt * 64) * TQKV;
    gload_lds16(ks + (size_t)(tid >> 3) * TQKV + (tid & 7) * 8,        lK + tid * 8);
    gload_lds16(ks + (size_t)((tid >> 3) + 32) * TQKV + (tid & 7) * 8, lK + 2048 + tid * 8);
    __syncthreads();

    f32x4 s[4];
#pragma unroll
    for (int nj = 0; nj < 4; ++nj) s[nj] = (f32x4){0.f, 0.f, 0.f, 0.f};
#pragma unroll
    for (int ks2 = 0; ks2 < 2; ++ks2)
#pragma unroll
      for (int nj = 0; nj < 4; ++nj) {
        s16x8 bk = *(const s16x8*)(lK + (nj * 16 + (lane & 15)) * 64 + ks2 * 32 + (lane >> 4) * 8);
        s[nj] = __builtin_amdgcn_mfma_f32_16x16x32_bf16(aq[ks2], bk, s[nj], 0, 0, 0);
      }

    const int kc = kt * 64 + (lane & 15);
#pragma unroll
    for (int r = 0; r < 4; ++r) {
      const int q = qrow + r;
      float v[4];
#pragma unroll
      for (int nj = 0; nj < 4; ++nj)
        v[nj] = (kc + nj * 16 <= q) ? s[nj][r] * 0.125f : -INFINITY;
      float tm = fmaxf(fmaxf(v[0], v[1]), fmaxf(v[2], v[3]));
      tm = fmaxf(tm, __shfl_xor(tm, 1));
      tm = fmaxf(tm, __shfl_xor(tm, 2));
      tm = fmaxf(tm, __shfl_xor(tm, 4));
      tm = fmaxf(tm, __shfl_xor(tm, 8));
      const float mn = fmaxf(m[r], tm);
      float p = __expf(v[0] - mn) + __expf(v[1] - mn) + __expf(v[2] - mn) + __expf(v[3] - mn);
      p += __shfl_xor(p, 1);
      p += __shfl_xor(p, 2);
      p += __shfl_xor(p, 4);
      p += __shfl_xor(p, 8);
      l[r] = l[r] * __expf(m[r] - mn) + p;
      m[r] = mn;
    }
  }
  if ((lane & 15) == 0) {
#pragma unroll
    for (int r = 0; r < 4; ++r) {
      mbuf[(size_t)bh * TT + qrow + r] = m[r];
      lbuf[(size_t)bh * TT + qrow + r] = l[r];
    }
  }
}

// ---------- attention pass 2: write w, PV, merged context ----------
__global__ __launch_bounds__(256) void attn_wv(const short* __restrict__ qkv,
                                               const short* __restrict__ vt,
                                               const float* __restrict__ mbuf,
                                               const float* __restrict__ lbuf,
                                               float* __restrict__ wout,
                                               short* __restrict__ merged) {
  __shared__ short lQ[64 * 64];
  __shared__ short lK[64 * 64];
  __shared__ short lV[64 * 64];
  __shared__ short lW[64 * 64];
  const int tid = threadIdx.x, lane = tid & 63, wid = tid >> 6;
  const int qt = blockIdx.x, bh = blockIdx.y;
  const int b = bh >> 4, h = bh & 15;

  const short* qsrc = qkv + ((size_t)(b * TT + qt * 64)) * TQKV + h * HD;
  gload_lds16(qsrc + (size_t)(tid >> 3) * TQKV + (tid & 7) * 8,        lQ + tid * 8);
  gload_lds16(qsrc + (size_t)((tid >> 3) + 32) * TQKV + (tid & 7) * 8, lQ + 2048 + tid * 8);
  __syncthreads();

  s16x8 aq[2];
  aq[0] = *(const s16x8*)(lQ + (wid * 16 + (lane & 15)) * 64 + (lane >> 4) * 8);
  aq[1] = *(const s16x8*)(lQ + (wid * 16 + (lane & 15)) * 64 + 32 + (lane >> 4) * 8);

  const int qrow = qt * 64 + wid * 16 + ((lane >> 4) << 2);
  float m[4], rl[4];
#pragma unroll
  for (int r = 0; r < 4; ++r) {
    m[r]  = mbuf[(size_t)bh * TT + qrow + r];
    rl[r] = 1.0f / lbuf[(size_t)bh * TT + qrow + r];
  }

  f32x4 o[4];
#pragma unroll
  for (int nj = 0; nj < 4; ++nj) o[nj] = (f32x4){0.f, 0.f, 0.f, 0.f};

  const short* ksrc0 = qkv + (size_t)(b * TT) * TQKV + EMB + h * HD;
  const short* vsrc0 = vt + (size_t)bh * HD * TT;

  for (int kt = 0; kt <= qt; ++kt) {
    __syncthreads();
    const short* ks = ksrc0 + (size_t)(kt * 64) * TQKV;
    gload_lds16(ks + (size_t)(tid >> 3) * TQKV + (tid & 7) * 8,        lK + tid * 8);
    gload_lds16(ks + (size_t)((tid >> 3) + 32) * TQKV + (tid & 7) * 8, lK + 2048 + tid * 8);
    const short* vs = vsrc0 + kt * 64;
    gload_lds16(vs + (size_t)(tid >> 3) * TT + (tid & 7) * 8,          lV + tid * 8);
    gload_lds16(vs + (size_t)((tid >> 3) + 32) * TT + (tid & 7) * 8,   lV + 2048 + tid * 8);
    __syncthreads();

    f32x4 s[4];
#pragma unroll
    for (int nj = 0; nj < 4; ++nj) s[nj] = (f32x4){0.f, 0.f, 0.f, 0.f};
#pragma unroll
    for (int ks2 = 0; ks2 < 2; ++ks2)
#pragma unroll
      for (int nj = 0; nj < 4; ++nj) {
        s16x8 bk = *(const s16x8*)(lK + (nj * 16 + (lane & 15)) * 64 + ks2 * 32 + (lane >> 4) * 8);
        s[nj] = __builtin_amdgcn_mfma_f32_16x16x32_bf16(aq[ks2], bk, s[nj], 0, 0, 0);
      }

    const int kc = kt * 64 + (lane & 15);
#pragma unroll
    for (int r = 0; r < 4; ++r) {
      const int q = qrow + r;
      float* wr = wout + ((size_t)bh * TT + q) * TT + kt * 64;
#pragma unroll
      for (int nj = 0; nj < 4; ++nj) {
        float wv = (kc + nj * 16 <= q) ? __expf(s[nj][r] * 0.125f - m[r]) * rl[r] : 0.f;
        wr[nj * 16 + (lane & 15)] = wv;
        lW[(wid * 16 + ((lane >> 4) << 2) + r) * 64 + nj * 16 + (lane & 15)] = f2bf(wv);
      }
    }
    __syncthreads();

#pragma unroll
    for (int ks2 = 0; ks2 < 2; ++ks2) {
      s16x8 aw = *(const s16x8*)(lW + (wid * 16 + (lane & 15)) * 64 + ks2 * 32 + (lane >> 4) * 8);
#pragma unroll
      for (int nj = 0; nj < 4; ++nj) {
        s16x8 bv = *(const s16x8*)(lV + (nj * 16 + (lane & 15)) * 64 + ks2 * 32 + (lane >> 4) * 8);
        o[nj] = __builtin_amdgcn_mfma_f32_16x16x32_bf16(aw, bv, o[nj], 0, 0, 0);
      }
    }
  }

  // zero-fill strictly-above-diagonal tiles of w
  for (int kt = qt + 1; kt < TT / 64; ++kt) {
    float* base = wout + ((size_t)bh * TT + qt * 64) * TT + kt * 64;
#pragma unroll
    for (int j = 0; j < 4; ++j) {
      int u = tid + j * 256;
      int row = u >> 4, c4 = (u & 15) * 4;
      *(f32x4*)(base + (size_t)row * TT + c4) = (f32x4){0.f, 0.f, 0.f, 0.f};
    }
  }

  // merged context [B*T, EMB] bf16
#pragma unroll
  for (int nj = 0; nj < 4; ++nj)
#pragma unroll
    for (int r = 0; r < 4; ++r)
      merged[(size_t)(b * TT + qrow + r) * EMB + h * HD + nj * 16 + (lane & 15)] = f2bf(o[nj][r]);
}

// ---------- host launcher ----------
extern "C" void kernel_launch(void* const* d_in, const int* in_sizes, int n_in,
                              void* d_out, int out_size, void* d_ws, size_t ws_size,
                              hipStream_t stream) {
  const float* x  = (const float*)d_in[0];
  // d_in[1] = mask (causal triu, recomputed from indices -> unused)
  const float* WQ = (const float*)d_in[2];
  const float* WK = (const float*)d_in[3];
  const float* WV = (const float*)d_in[4];
  const float* WO = (const float*)d_in[5];

  float* y    = (float*)d_out;                       // [B,T,E]
  float* wout = (float*)d_out + (size_t)NB * TT * EMB; // [B,H,T,T]

  char* ws = (char*)d_ws;
  short* xb     = (short*)(ws + 0);          //  8,388,608 B  [4096,1024] bf16
  short* wqkv   = (short*)(ws + 8388608);    //  6,291,456 B  [3072,1024] bf16
  short* wob    = (short*)(ws + 14680064);   //  2,097,152 B  [1024,1024] bf16
  short* qkvb   = (short*)(ws + 16777216);   // 25,165,824 B  [4096,3072] bf16
  short* vtb    = (short*)(ws + 41943040);   //  8,388,608 B  [32,64,2048] bf16
  float* mbuf   = (float*)(ws + 50331648);   //    262,144 B  [32,2048] f32
  float* lbuf   = (float*)(ws + 50593792);   //    262,144 B
  short* merged = (short*)(ws + 50855936);   //  8,388,608 B  [4096,1024] bf16
  // total ws use: 59,244,544 B

  // 1. convert inputs to bf16
  cvt4<<<4096, 256, 0, stream>>>(x, xb, 1048576);
  cvt4<<<1024, 256, 0, stream>>>(WQ, wqkv, 262144);
  cvt4<<<1024, 256, 0, stream>>>(WK, wqkv + 1048576, 262144);
  cvt4<<<1024, 256, 0, stream>>>(WV, wqkv + 2097152, 262144);
  cvt4<<<1024, 256, 0, stream>>>(WO, wob, 262144);

  // 2. packed QKV projection: [4096,3072] = xb @ wqkv^T
  gemm_nt<1><<<dim3(24, 32), 256, 0, stream>>>(xb, wqkv, qkvb, 4096, 3072, 1024);

  // 3. V transpose -> [bh][d][t]
  transpose_v<<<dim3(32, 32), 256, 0, stream>>>(qkvb, vtb);

  // 4. softmax stats
  attn_ml<<<dim3(32, 32), 256, 0, stream>>>(qkvb, mbuf, lbuf);

  // 5. w + PV + merged
  attn_wv<<<dim3(32, 32), 256, 0, stream>>>(qkvb, vtb, mbuf, lbuf, wout, merged);

  // 6. output projection: y = merged @ WO^T (fp32 out)
  gemm_nt<0><<<dim3(8, 32), 256, 0, stream>>>(merged, wob, y, 4096, 1024, 1024);
}